// Round 14
// baseline (450.601 us; speedup 1.0000x reference)
//
#include <hip/hip_runtime.h>
#include <stdint.h>

#define TOKENS 8192
#define KIN    4096
#define NOUT   11008

// ---- 256x256 GEMM geometry (i8, BK=128 => 128 B/row) ----
#define BM 256
#define BN 256
#define BK 128
#define NT    (KIN / BK)      // 32 K-tiles
#define NTROW (TOKENS / BM)   // 32
#define NTCOL (NOUT / BN)     // 43
#define NWG   (NTROW * NTCOL) // 1376 = 8 XCDs x 172

using i32x4  = __attribute__((ext_vector_type(4)))  int;
using i32x16 = __attribute__((ext_vector_type(16))) int;

static __device__ __forceinline__ void gload_lds16(const void* g, void* l) {
  __builtin_amdgcn_global_load_lds((const __attribute__((address_space(1))) void*)g,
                                   (__attribute__((address_space(3))) void*)l,
                                   16, 0, 0);
}

static __device__ __forceinline__ int clamp_q(float f) {
  int q = (int)rintf(f);
  q = q > 127 ? 127 : q;
  q = q < -127 ? -127 : q;
  return q;
}

static __device__ __forceinline__ int pack4(int a, int b, int c, int d) {
  return (a & 0xff) | ((b & 0xff) << 8) | ((c & 0xff) << 16) | ((d & 0xff) << 24);
}

// ---- kernel 1: fused quantization (weight rows, then input rows; one launch) ----
__global__ __launch_bounds__(256) void quant_fused_k(const float* __restrict__ W,
                                                     const float* __restrict__ X,
                                                     signed char* __restrict__ Wq,
                                                     signed char* __restrict__ Xq,
                                                     float* __restrict__ scale_w,
                                                     float* __restrict__ scale_x) {
  const int bid = blockIdx.x;
  const int t   = threadIdx.x;
  if (bid < NOUT) {
    const int row = bid;
    const float4* wr = reinterpret_cast<const float4*>(W + (size_t)row * KIN);
    float4 v[4];
    double s = 0.0;
#pragma unroll
    for (int i = 0; i < 4; ++i) {
      v[i] = wr[t + i * 256];
      s += fabs((double)v[i].x) + fabs((double)v[i].y) +
           fabs((double)v[i].z) + fabs((double)v[i].w);
    }
#pragma unroll
    for (int off = 32; off > 0; off >>= 1) s += __shfl_down(s, off);
    __shared__ double redd[4];
    if ((t & 63) == 0) redd[t >> 6] = s;
    __syncthreads();
    const float sc = (float)((redd[0] + redd[1] + redd[2] + redd[3]) * (1.0 / KIN));
    if (t == 0) scale_w[row] = sc;
    int* qr = reinterpret_cast<int*>(Wq + (size_t)row * KIN);
#pragma unroll
    for (int i = 0; i < 4; ++i)
      qr[t + i * 256] = pack4(clamp_q(v[i].x / sc), clamp_q(v[i].y / sc),
                              clamp_q(v[i].z / sc), clamp_q(v[i].w / sc));
  } else {
    const int row = bid - NOUT;
    const float4* xr = reinterpret_cast<const float4*>(X + (size_t)row * KIN);
    float4 v[4];
    float amax = 0.f;
#pragma unroll
    for (int i = 0; i < 4; ++i) {
      v[i] = xr[t + i * 256];
      amax = fmaxf(amax, fmaxf(fmaxf(fabsf(v[i].x), fabsf(v[i].y)),
                               fmaxf(fabsf(v[i].z), fabsf(v[i].w))));
    }
#pragma unroll
    for (int off = 32; off > 0; off >>= 1) amax = fmaxf(amax, __shfl_down(amax, off));
    __shared__ float redf[4];
    if ((t & 63) == 0) redf[t >> 6] = amax;
    __syncthreads();
    amax = fmaxf(fmaxf(redf[0], redf[1]), fmaxf(redf[2], redf[3]));
    amax = fmaxf(amax, 1e-30f);
    const float inv = 127.0f / amax;
    if (t == 0) scale_x[row] = amax * (1.0f / 127.0f);
    int* qr = reinterpret_cast<int*>(Xq + (size_t)row * KIN);
#pragma unroll
    for (int i = 0; i < 4; ++i)
      qr[t + i * 256] = pack4(clamp_q(v[i].x * inv), clamp_q(v[i].y * inv),
                              clamp_q(v[i].z * inv), clamp_q(v[i].w * inv));
  }
}

// ---- kernel 2: 256x256x128 i8 GEMM, 32x32x32 MFMA, minimal-barrier schedule ----
// out[t,o] = s_x[t]*s_w[o]*(Xq[t,:].Wq[o,:])_i32 + bias[o].  Row-major [row][K] i8.
//
// R14 = R13 skeleton with mfma_i32_32x32x32_i8:
//   - 12% higher uench ceiling (4404 vs 3944 TOPS, m55 vs m16)
//   - half the MFMA instruction count -> per-region MFMA clusters ~146cy
//     (16 x ~9.1cy) instead of ~82cy -> ds_read drain hides better under them
//   - identical LDS bytes / staging / swizzle; fragment regs unchanged (64)
// Per wave (128x64 output): 4 m-frags (32 rows) x 2 n-frags (32 cols) x 4 k-slices.
// A/B operand layout (extends R4-verified 16x16x64 pattern): lane l holds
// row/col = l&31, k = (l>>5)*16 + elem (16 contiguous K-bytes = one 16B slot).
// C/D layout [m74/m101]: col = lane&31, row = (reg&3) + 8*(reg>>2) + 4*(lane>>5).
//
// Barriers (consumption forces completion):
//   region1: read A m0-1 (8 b128) + B n0-1 all ks (8 b128); 16 MFMA (m0-1 x n0-1)
//   bar1 (all B-cur + A m0-1 reads consumed) ; stage B(t+2)->cur
//   region2: read A m2-3 (8 b128); 16 MFMA (m2-3 x n0-1)
//   bar2 (all A-cur reads consumed) ; stage A(t+2)->cur
//   vmcnt(8) counted (tile t+1 landed; t+2's 8 loads in flight) ; bar3
__global__ __launch_bounds__(512, 2) void gemm_k(const signed char* __restrict__ Xq,
                                                 const signed char* __restrict__ Wq,
                                                 const float* __restrict__ scale_x,
                                                 const float* __restrict__ scale_w,
                                                 const float* __restrict__ bias,
                                                 float* __restrict__ out) {
  __shared__ alignas(16) char lds[131072];

  // ---- supertile swizzle (R6): 1376 = 8 XCDs x 172; 172 = 10 x (4x4) + 4x3 ----
  const int xcd = (int)blockIdx.x & 7;
  const int seq = (int)blockIdx.x >> 3;          // 0..171
  int trow, tcol;
  if (seq < 160) {
    const int chunk = seq >> 4;                  // 0..9
    const int rem   = seq & 15;
    trow = xcd * 4 + (rem >> 2);
    tcol = chunk * 4 + (rem & 3);
  } else {
    const int rem = seq - 160;                   // 0..11
    trow = xcd * 4 + rem / 3;
    tcol = 40 + rem % 3;
  }

  const int tid  = (int)threadIdx.x;
  const int lane = tid & 63;
  const int wave = tid >> 6;   // 0..7
  const int wm   = wave >> 2;  // 0..1 : M half (128 rows)
  const int wn   = wave & 3;   // 0..3 : N quarter (64 cols)

  // ---- staging lane addresses (inverse-swizzled global source, linear LDS dest) ----
  const int l8 = lane >> 3;                          // row within 8-row group
  const size_t rowb = (size_t)KIN;                   // 4096 B per row (i8)
  const int swzl = ((lane & 7) ^ l8) * 16;           // pre-swizzled slot within 128-B row chunk
  const char* gA = (const char*)Xq + (size_t)(trow * BM + wave * 16 + l8) * rowb + swzl;
  const char* gB = (const char*)Wq + (size_t)(tcol * BN + wave * 16 + l8) * rowb + swzl;
  char* lA = lds + wave * 2048;            // + buf*32768 + h*16384 (+1024 for 2nd gload)
  char* lB = lds + 65536 + wave * 2048;

#define STAGE(gp, lp, koff) do {                                             \
    gload_lds16((gp) + (koff), (lp));                                        \
    gload_lds16((gp) + (koff) + (size_t)(8 * 4096), (char*)(lp) + 1024);     \
  } while (0)

#define STAGE_B(CUR, KS) do {                                                \
    STAGE(gB,              lB + (CUR),         (KS));                        \
    STAGE(gB + 128 * rowb, lB + (CUR) + 16384, (KS));                        \
  } while (0)

#define STAGE_A(CUR, KS) do {                                                \
    STAGE(gA,              lA + (CUR),         (KS));                        \
    STAGE(gA + 128 * rowb, lA + (CUR) + 16384, (KS));                        \
  } while (0)

  // ---- ds_read bases (swizzled), 32x32 fragments ----
  const int l31 = lane & 31;
  const int l5  = lane >> 5;                         // 0/1 -> k-slot half
  // slot index for k-slice ks: ks*2 + l5 ; swizzle XOR (row&7)
  int swzk[4];
#pragma unroll
  for (int ks = 0; ks < 4; ++ks)
    swzk[ks] = ((ks * 2 + l5) << 4) ^ ((l31 & 7) << 4);
  const char* rdA = lds + wm * 16384 + l31 * 128;            // + mf*4096
  const char* rdB = lds + 65536 + wn * 8192 + l31 * 128;     // + nf*4096

  i32x16 acc[4][2];
#pragma unroll
  for (int m = 0; m < 4; ++m)
#pragma unroll
    for (int n = 0; n < 2; ++n)
#pragma unroll
      for (int e = 0; e < 16; ++e) acc[m][n][e] = 0;
  i32x4 afr[2][4], bfr[2][4];   // afr reused m0-1 then m2-3

#define SB() __builtin_amdgcn_sched_barrier(0)
#define BAR() do { SB(); __builtin_amdgcn_s_barrier(); SB(); } while (0)

#define TILE(T, CUR) do {                                                     \
    const size_t kS = (size_t)((T) + 2) * 128;                                \
    /* region 1: A m0-1 + B n0-1 (all ks); MFMA m0-1 x n0-1 */                \
    _Pragma("unroll") for (int mf = 0; mf < 2; ++mf)                          \
    _Pragma("unroll") for (int ks = 0; ks < 4; ++ks)                          \
      afr[mf][ks] = *(const i32x4*)(rdA + (CUR) + mf * 4096 + swzk[ks]);      \
    _Pragma("unroll") for (int nf = 0; nf < 2; ++nf)                          \
    _Pragma("unroll") for (int ks = 0; ks < 4; ++ks)                          \
      bfr[nf][ks] = *(const i32x4*)(rdB + (CUR) + nf * 4096 + swzk[ks]);      \
    _Pragma("unroll") for (int mf = 0; mf < 2; ++mf)                          \
    _Pragma("unroll") for (int nf = 0; nf < 2; ++nf)                          \
    _Pragma("unroll") for (int ks = 0; ks < 4; ++ks)                          \
      acc[mf][nf] = __builtin_amdgcn_mfma_i32_32x32x32_i8(                    \
          afr[mf][ks], bfr[nf][ks], acc[mf][nf], 0, 0, 0);                    \
    BAR();  /* bar1: all B-cur (and A m0-1) reads consumed by all waves */    \
    if ((T) + 2 < NT) STAGE_B((CUR), kS);                                     \
    /* region 2: A m2-3; MFMA m2-3 x n0-1 */                                  \
    _Pragma("unroll") for (int mf = 0; mf < 2; ++mf)                          \
    _Pragma("unroll") for (int ks = 0; ks < 4; ++ks)                          \
      afr[mf][ks] = *(const i32x4*)(rdA + (CUR) + (2 + mf) * 4096 + swzk[ks]);\
    _Pragma("unroll") for (int mf = 0; mf < 2; ++mf)                          \
    _Pragma("unroll") for (int nf = 0; nf < 2; ++nf)                          \
    _Pragma("unroll") for (int ks = 0; ks < 4; ++ks)                          \
      acc[2 + mf][nf] = __builtin_amdgcn_mfma_i32_32x32x32_i8(                \
          afr[mf][ks], bfr[nf][ks], acc[2 + mf][nf], 0, 0, 0);                \
    BAR();  /* bar2: all A-cur reads consumed by all waves */                 \
    if ((T) + 2 < NT) STAGE_A((CUR), kS);                                     \
    if ((T) < NT - 2) { asm volatile("s_waitcnt vmcnt(8)" ::: "memory"); }    \
    else              { asm volatile("s_waitcnt vmcnt(0)" ::: "memory"); }    \
    BAR();  /* bar3: tile T+1 staged data visible to all waves */             \
  } while (0)

  // ---- prologue: stage tiles 0 and 1 fully (16 loads); wait tile0 (vmcnt(8)) ----
  STAGE_A(0,     0);
  STAGE_B(0,     0);
  STAGE_A(32768, 128);
  STAGE_B(32768, 128);
  asm volatile("s_waitcnt vmcnt(8)" ::: "memory");  // tile0 landed; tile1 in flight
  BAR();

  for (int tt = 0; tt < NT; tt += 2) {
    TILE(tt,     0);
    TILE(tt + 1, 32768);
  }

  // ---- epilogue: C/D 32x32 layout: col = lane&31, row = (r&3)+8*(r>>2)+4*l5 ----
  const int gr0 = trow * BM + wm * 128 + 4 * l5;
  const int gc0 = tcol * BN + wn * 64 + l31;
#pragma unroll
  for (int nf = 0; nf < 2; ++nf) {
    const int gc = gc0 + nf * 32;
    const float sw = scale_w[gc];
    const float bb = bias[gc];
#pragma unroll
    for (int mf = 0; mf < 4; ++mf) {
#pragma unroll
      for (int rq = 0; rq < 4; ++rq) {
        const int rowb4 = gr0 + mf * 32 + rq * 8;    // 4 consecutive rows rr=0..3
        const float4 sx4 = *reinterpret_cast<const float4*>(&scale_x[rowb4]);
        const size_t ob = (size_t)rowb4 * NOUT + gc;
        __builtin_nontemporal_store((float)acc[mf][nf][rq * 4 + 0] * (sx4.x * sw) + bb, &out[ob]);
        __builtin_nontemporal_store((float)acc[mf][nf][rq * 4 + 1] * (sx4.y * sw) + bb, &out[ob + NOUT]);
        __builtin_nontemporal_store((float)acc[mf][nf][rq * 4 + 2] * (sx4.z * sw) + bb, &out[ob + 2 * (size_t)NOUT]);
        __builtin_nontemporal_store((float)acc[mf][nf][rq * 4 + 3] * (sx4.w * sw) + bb, &out[ob + 3 * (size_t)NOUT]);
      }
    }
  }
#undef STAGE
#undef STAGE_A
#undef STAGE_B
#undef TILE
#undef SB
#undef BAR
}

extern "C" void kernel_launch(void* const* d_in, const int* in_sizes, int n_in,
                              void* d_out, int out_size, void* d_ws, size_t ws_size,
                              hipStream_t stream) {
  const float* X  = (const float*)d_in[0];   // [8192, 4096] fp32
  const float* W  = (const float*)d_in[1];   // [11008, 4096] fp32
  const float* Bi = (const float*)d_in[2];   // [11008] fp32
  float* out = (float*)d_out;                // [8192, 11008] fp32

  const size_t xq_bytes = (size_t)TOKENS * KIN;      // 32 MiB
  const size_t wq_bytes = (size_t)NOUT * KIN;        // 43 MiB
  const size_t need = xq_bytes + wq_bytes + (size_t)(NOUT + TOKENS) * sizeof(float);
  if (ws_size < need) return;  // needs ~76 MB scratch

  char* ws = (char*)d_ws;
  signed char* Xq = (signed char*)ws;
  signed char* Wq = (signed char*)(ws + xq_bytes);
  float* scale_w = (float*)(ws + xq_bytes + wq_bytes);
  float* scale_x = scale_w + NOUT;

  quant_fused_k<<<NOUT + TOKENS, 256, 0, stream>>>(W, X, Wq, Xq, scale_w, scale_x);
  gemm_k<<<NWG, 512, 0, stream>>>(Xq, Wq, scale_x, scale_w, Bi, out);
}

// Round 15
// 422.383 us; speedup vs baseline: 1.0668x; 1.0668x over previous
//
#include <hip/hip_runtime.h>
#include <stdint.h>

#define TOKENS 8192
#define KIN    4096
#define NOUT   11008

// ---- 256x256 GEMM geometry (i8, BK=128 => 128 B/row) ----
#define BM 256
#define BN 256
#define BK 128
#define NT    (KIN / BK)      // 32 K-tiles
#define NTROW (TOKENS / BM)   // 32
#define NTCOL (NOUT / BN)     // 43
#define NWG   (NTROW * NTCOL) // 1376 = 8 XCDs x 172

using i32x4 = __attribute__((ext_vector_type(4))) int;

static __device__ __forceinline__ void gload_lds16(const void* g, void* l) {
  __builtin_amdgcn_global_load_lds((const __attribute__((address_space(1))) void*)g,
                                   (__attribute__((address_space(3))) void*)l,
                                   16, 0, 0);
}

static __device__ __forceinline__ int clamp_q(float f) {
  int q = (int)rintf(f);
  q = q > 127 ? 127 : q;
  q = q < -127 ? -127 : q;
  return q;
}

static __device__ __forceinline__ int pack4(int a, int b, int c, int d) {
  return (a & 0xff) | ((b & 0xff) << 8) | ((c & 0xff) << 16) | ((d & 0xff) << 24);
}

// ---- kernel 1: fused quantization (weight rows, then input rows; one launch) ----
__global__ __launch_bounds__(256) void quant_fused_k(const float* __restrict__ W,
                                                     const float* __restrict__ X,
                                                     signed char* __restrict__ Wq,
                                                     signed char* __restrict__ Xq,
                                                     float* __restrict__ scale_w,
                                                     float* __restrict__ scale_x) {
  const int bid = blockIdx.x;
  const int t   = threadIdx.x;
  if (bid < NOUT) {
    const int row = bid;
    const float4* wr = reinterpret_cast<const float4*>(W + (size_t)row * KIN);
    float4 v[4];
    double s = 0.0;
#pragma unroll
    for (int i = 0; i < 4; ++i) {
      v[i] = wr[t + i * 256];
      s += fabs((double)v[i].x) + fabs((double)v[i].y) +
           fabs((double)v[i].z) + fabs((double)v[i].w);
    }
#pragma unroll
    for (int off = 32; off > 0; off >>= 1) s += __shfl_down(s, off);
    __shared__ double redd[4];
    if ((t & 63) == 0) redd[t >> 6] = s;
    __syncthreads();
    const float sc = (float)((redd[0] + redd[1] + redd[2] + redd[3]) * (1.0 / KIN));
    if (t == 0) scale_w[row] = sc;
    int* qr = reinterpret_cast<int*>(Wq + (size_t)row * KIN);
#pragma unroll
    for (int i = 0; i < 4; ++i)
      qr[t + i * 256] = pack4(clamp_q(v[i].x / sc), clamp_q(v[i].y / sc),
                              clamp_q(v[i].z / sc), clamp_q(v[i].w / sc));
  } else {
    const int row = bid - NOUT;
    const float4* xr = reinterpret_cast<const float4*>(X + (size_t)row * KIN);
    float4 v[4];
    float amax = 0.f;
#pragma unroll
    for (int i = 0; i < 4; ++i) {
      v[i] = xr[t + i * 256];
      amax = fmaxf(amax, fmaxf(fmaxf(fabsf(v[i].x), fabsf(v[i].y)),
                               fmaxf(fabsf(v[i].z), fabsf(v[i].w))));
    }
#pragma unroll
    for (int off = 32; off > 0; off >>= 1) amax = fmaxf(amax, __shfl_down(amax, off));
    __shared__ float redf[4];
    if ((t & 63) == 0) redf[t >> 6] = amax;
    __syncthreads();
    amax = fmaxf(fmaxf(redf[0], redf[1]), fmaxf(redf[2], redf[3]));
    amax = fmaxf(amax, 1e-30f);
    const float inv = 127.0f / amax;
    if (t == 0) scale_x[row] = amax * (1.0f / 127.0f);
    int* qr = reinterpret_cast<int*>(Xq + (size_t)row * KIN);
#pragma unroll
    for (int i = 0; i < 4; ++i)
      qr[t + i * 256] = pack4(clamp_q(v[i].x * inv), clamp_q(v[i].y * inv),
                              clamp_q(v[i].z * inv), clamp_q(v[i].w * inv));
  }
}

// ---- kernel 2: 256x256x128 i8 GEMM, minimal-barrier schedule (best measured) ----
// out[t,o] = s_x[t]*s_w[o]*(Xq[t,:].Wq[o,:])_i32 + bias[o].  Row-major [row][K] i8.
//
// FINAL (R13 config, 418.9us): 16x16x64 MFMA (R14's 32x32 regressed: 3.4e7 bank
// conflicts), 3 barriers/K-tile, counted vmcnt(8), both-sides slot^(row&7)
// swizzle (0 conflicts), supertile XCD swizzle, no setprio (m190), NT stores.
// Barrier invariants:
//   bar1: all waves consumed B-cur reads  -> stage B(t+2)->cur safe after it
//   bar2: all waves consumed A-cur reads  -> stage A(t+2)->cur safe after it
//   bar3 + vmcnt(8): tile t+1 staged data visible; tile t+2's 8 loads in flight
// "Consumed" = every ds_read feeds an MFMA before the next barrier (compiler's
// counted lgkm waits enforce completion before the consuming MFMA issues).
// sched_barrier(0) on BOTH sides of each s_barrier pins MFMAs/stages (rule #18).
__global__ __launch_bounds__(512, 2) void gemm_k(const signed char* __restrict__ Xq,
                                                 const signed char* __restrict__ Wq,
                                                 const float* __restrict__ scale_x,
                                                 const float* __restrict__ scale_w,
                                                 const float* __restrict__ bias,
                                                 float* __restrict__ out) {
  __shared__ alignas(16) char lds[131072];

  // ---- supertile swizzle (R6): 1376 = 8 XCDs x 172; 172 = 10 x (4x4) + 4x3 ----
  const int xcd = (int)blockIdx.x & 7;
  const int seq = (int)blockIdx.x >> 3;          // 0..171
  int trow, tcol;
  if (seq < 160) {
    const int chunk = seq >> 4;                  // 0..9
    const int rem   = seq & 15;
    trow = xcd * 4 + (rem >> 2);
    tcol = chunk * 4 + (rem & 3);
  } else {
    const int rem = seq - 160;                   // 0..11
    trow = xcd * 4 + rem / 3;
    tcol = 40 + rem % 3;
  }

  const int tid  = (int)threadIdx.x;
  const int lane = tid & 63;
  const int wave = tid >> 6;   // 0..7
  const int wm   = wave >> 2;  // 0..1 : M half (128 rows)
  const int wn   = wave & 3;   // 0..3 : N quarter (64 cols)

  // ---- staging lane addresses (inverse-swizzled global source, linear LDS dest) ----
  const int l8 = lane >> 3;                          // row within 8-row group
  const size_t rowb = (size_t)KIN;                   // 4096 B per row (i8)
  const int swzl = ((lane & 7) ^ l8) * 16;           // pre-swizzled slot within 128-B row chunk
  const char* gA = (const char*)Xq + (size_t)(trow * BM + wave * 16 + l8) * rowb + swzl;
  const char* gB = (const char*)Wq + (size_t)(tcol * BN + wave * 16 + l8) * rowb + swzl;
  char* lA = lds + wave * 2048;            // + buf*32768 + h*16384 (+1024 for 2nd gload)
  char* lB = lds + 65536 + wave * 2048;

#define STAGE(gp, lp, koff) do {                                             \
    gload_lds16((gp) + (koff), (lp));                                        \
    gload_lds16((gp) + (koff) + (size_t)(8 * 4096), (char*)(lp) + 1024);     \
  } while (0)

#define STAGE_B(CUR, KS) do {                                                \
    STAGE(gB,              lB + (CUR),         (KS));                        \
    STAGE(gB + 128 * rowb, lB + (CUR) + 16384, (KS));                        \
  } while (0)

#define STAGE_A(CUR, KS) do {                                                \
    STAGE(gA,              lA + (CUR),         (KS));                        \
    STAGE(gA + 128 * rowb, lA + (CUR) + 16384, (KS));                        \
  } while (0)

  // ---- ds_read bases (swizzled) ----
  const int lr = lane & 15;
  const int hi = lane >> 4;                          // 0..3 -> k-slot within 64-B k-slice
  const int swz0 = (hi * 16) ^ ((lr & 7) << 4);
  const int swz[2] = { swz0, swz0 ^ 64 };            // ks=0 / ks=1 (XOR: bit6 overlaps swizzle field)
  const char* rdA = lds + wm * 16384 + lr * 128;
  const char* rdB = lds + 65536 + (wn >> 1) * 16384 + ((wn & 1) * 64 + lr) * 128;

  i32x4 acc[8][4];
#pragma unroll
  for (int m = 0; m < 8; ++m)
#pragma unroll
    for (int n = 0; n < 4; ++n) acc[m][n] = (i32x4){0, 0, 0, 0};
  i32x4 afr[4][2], bfr[4][2];   // single set; afr reused m0-3 then m4-7

#define SB() __builtin_amdgcn_sched_barrier(0)
#define BAR() do { SB(); __builtin_amdgcn_s_barrier(); SB(); } while (0)

#define TILE(T, CUR) do {                                                     \
    const size_t kS = (size_t)((T) + 2) * 128;                                \
    /* region 1: A m0-3 + B n0-3 reads; MFMA m0-3 x n0-3 */                   \
    _Pragma("unroll") for (int mf = 0; mf < 4; ++mf) {                        \
      afr[mf][0] = *(const i32x4*)(rdA + (CUR) + mf * 2048 + swz[0]);         \
      afr[mf][1] = *(const i32x4*)(rdA + (CUR) + mf * 2048 + swz[1]);         \
    }                                                                         \
    _Pragma("unroll") for (int nf = 0; nf < 4; ++nf) {                        \
      bfr[nf][0] = *(const i32x4*)(rdB + (CUR) + nf * 2048 + swz[0]);         \
      bfr[nf][1] = *(const i32x4*)(rdB + (CUR) + nf * 2048 + swz[1]);         \
    }                                                                         \
    _Pragma("unroll") for (int mf = 0; mf < 4; ++mf)                          \
    _Pragma("unroll") for (int nf = 0; nf < 4; ++nf)                          \
    _Pragma("unroll") for (int kk = 0; kk < 2; ++kk)                          \
      acc[mf][nf] = __builtin_amdgcn_mfma_i32_16x16x64_i8(                    \
          afr[mf][kk], bfr[nf][kk], acc[mf][nf], 0, 0, 0);                    \
    BAR();  /* bar1: B-cur reads consumed by all waves */                     \
    if ((T) + 2 < NT) STAGE_B((CUR), kS);                                     \
    _Pragma("unroll") for (int mf = 0; mf < 4; ++mf) {                        \
      afr[mf][0] = *(const i32x4*)(rdA + (CUR) + (4 + mf) * 2048 + swz[0]);   \
      afr[mf][1] = *(const i32x4*)(rdA + (CUR) + (4 + mf) * 2048 + swz[1]);   \
    }                                                                         \
    _Pragma("unroll") for (int mf = 0; mf < 4; ++mf)                          \
    _Pragma("unroll") for (int nf = 2; nf < 4; ++nf)                          \
    _Pragma("unroll") for (int kk = 0; kk < 2; ++kk)                          \
      acc[4 + mf][nf] = __builtin_amdgcn_mfma_i32_16x16x64_i8(                \
          afr[mf][kk], bfr[nf][kk], acc[4 + mf][nf], 0, 0, 0);                \
    BAR();  /* bar2: A-cur reads consumed by all waves */                     \
    if ((T) + 2 < NT) STAGE_A((CUR), kS);                                     \
    _Pragma("unroll") for (int mf = 0; mf < 4; ++mf)                          \
    _Pragma("unroll") for (int nf = 0; nf < 2; ++nf)                          \
    _Pragma("unroll") for (int kk = 0; kk < 2; ++kk)                          \
      acc[4 + mf][nf] = __builtin_amdgcn_mfma_i32_16x16x64_i8(                \
          afr[mf][kk], bfr[nf][kk], acc[4 + mf][nf], 0, 0, 0);                \
    if ((T) < NT - 2) { asm volatile("s_waitcnt vmcnt(8)" ::: "memory"); }    \
    else              { asm volatile("s_waitcnt vmcnt(0)" ::: "memory"); }    \
    BAR();  /* bar3: tile T+1 staged data visible to all waves */             \
  } while (0)

  // ---- prologue: stage tiles 0 and 1 fully (16 loads); wait tile0 (vmcnt(8)) ----
  STAGE_A(0,     0);
  STAGE_B(0,     0);
  STAGE_A(32768, 128);
  STAGE_B(32768, 128);
  asm volatile("s_waitcnt vmcnt(8)" ::: "memory");  // tile0 landed; tile1 in flight
  BAR();

  for (int tt = 0; tt < NT; tt += 2) {
    TILE(tt,     0);
    TILE(tt + 1, 32768);
  }

  // ---- epilogue: C/D layout col = lane&15, row = (lane>>4)*4 + reg (dtype-independent) ----
  const int gr_base = trow * BM + wm * 128 + hi * 4;
  const int gc_base = tcol * BN + wn * 64 + lr;
  float sx[8][4];
#pragma unroll
  for (int mf = 0; mf < 8; ++mf)
#pragma unroll
    for (int j = 0; j < 4; ++j) sx[mf][j] = scale_x[gr_base + mf * 16 + j];
#pragma unroll
  for (int nf = 0; nf < 4; ++nf) {
    const int gc = gc_base + nf * 16;
    const float sw = scale_w[gc];
    const float bb = bias[gc];
#pragma unroll
    for (int mf = 0; mf < 8; ++mf) {
      const size_t rb = (size_t)(gr_base + mf * 16) * NOUT + gc;
#pragma unroll
      for (int j = 0; j < 4; ++j)
        __builtin_nontemporal_store((float)acc[mf][nf][j] * (sx[mf][j] * sw) + bb,
                                    &out[rb + (size_t)j * NOUT]);
    }
  }
#undef STAGE
#undef STAGE_A
#undef STAGE_B
#undef TILE
#undef SB
#undef BAR
}

extern "C" void kernel_launch(void* const* d_in, const int* in_sizes, int n_in,
                              void* d_out, int out_size, void* d_ws, size_t ws_size,
                              hipStream_t stream) {
  const float* X  = (const float*)d_in[0];   // [8192, 4096] fp32
  const float* W  = (const float*)d_in[1];   // [11008, 4096] fp32
  const float* Bi = (const float*)d_in[2];   // [11008] fp32
  float* out = (float*)d_out;                // [8192, 11008] fp32

  const size_t xq_bytes = (size_t)TOKENS * KIN;      // 32 MiB
  const size_t wq_bytes = (size_t)NOUT * KIN;        // 43 MiB
  const size_t need = xq_bytes + wq_bytes + (size_t)(NOUT + TOKENS) * sizeof(float);
  if (ws_size < need) return;  // needs ~76 MB scratch

  char* ws = (char*)d_ws;
  signed char* Xq = (signed char*)ws;
  signed char* Wq = (signed char*)(ws + xq_bytes);
  float* scale_w = (float*)(ws + xq_bytes + wq_bytes);
  float* scale_x = scale_w + NOUT;

  quant_fused_k<<<NOUT + TOKENS, 256, 0, stream>>>(W, X, Wq, Xq, scale_w, scale_x);
  gemm_k<<<NWG, 512, 0, stream>>>(Xq, Wq, scale_x, scale_w, Bi, out);
}